// Round 3
// baseline (91.792 us; speedup 1.0000x reference)
//
#include <hip/hip_runtime.h>
#include <math.h>

#define R 2048
#define C 1024
#define CH 8
#define K 64  // CH*BA

// Output layout (floats), reference return order:
#define OFF_P     0
#define OFF_TOT   (R*K)            // 131072
#define OFF_MAX   (OFF_TOT + 8)
#define OFF_NCOL  (OFF_MAX + 8)
#define OFF_NROW  (OFF_NCOL + 8)
#define OFF_NNZ   (OFF_NROW + 8)
#define OFF_DEN   (OFF_NNZ + 64)
#define OFF_SEL   (OFF_DEN + 8)

// ws layout (floats) -- ALL plain stores, every slot written before read,
// so the harness's 0xAA poison never needs clearing:
#define WS_CP   0                    // colpart[16][8][1024]: per-row-chunk
                                     //   partial products, [rc][ch][c]
#define WS_NP   131072               // nnzpart[256][64]: per-block nnz partials
#define WS_NR   (WS_NP + 16384)      // nrpart[16][8]: num_row partials (cb==0)
#define WS_SEL  (WS_NR + 128)        // selpart[16]

// ---------------------------------------------------------------- kernel 1
// grid 256 = 16 row-chunks (128 rows) x 16 col-tiles (64 cols), block 512.
// Each wave owns 16 rows: softmax (recomputed per col-tile; W/g are L2-hot),
// D-tile pass, column products, nnz -- all fused in one 16-iteration loop.
__global__ __launch_bounds__(512) void k1(
    const float* __restrict__ W, const float* __restrict__ Dm,
    const float* __restrict__ g, float* __restrict__ P,
    float* __restrict__ ws)
{
    const int tid  = threadIdx.x;
    const int lane = tid & 63;
    const int w    = tid >> 6;           // wave 0..7
    const int rc   = blockIdx.x >> 4;    // row chunk
    const int cb   = blockIdx.x & 15;    // col tile
    const int row0 = rc * 128 + w * 16;  // this wave's first row
    const int col  = cb * 64 + lane;

    __shared__ float partp[8][8][64];    // [wave][ch][col-lane] products
    __shared__ float rn[8][64];          // nnz partials per wave
    __shared__ float rp[8][8];           // num_row partials per wave
    __shared__ float rsel[8];

    float pr[8] = {1.f,1.f,1.f,1.f,1.f,1.f,1.f,1.f};
    float nnz_l = 0.f, acc_srow = 0.f, acc_sel = 0.f;

    #pragma unroll 4
    for (int i = 0; i < 16; ++i) {
        const int row = row0 + i;
        float d = Dm[(size_t)row * C + col];          // issue early, use late

        // softmax over the row's 64 logits (whole wave = one row)
        float z = W[row * K + lane] + g[row * K + lane];
        float m = z;
        #pragma unroll
        for (int off = 32; off >= 1; off >>= 1)
            m = fmaxf(m, __shfl_xor(m, off, 64));
        float e = __expf(z - m);
        float s = e;
        #pragma unroll
        for (int off = 32; off >= 1; off >>= 1)
            s += __shfl_xor(s, off, 64);
        float p = e * __builtin_amdgcn_rcpf(s);
        if (cb == 0) P[row * K + lane] = p;

        // per-channel (8-lane group) product of (1-p) and sum of p
        float om = 1.0f - p, sc = p;
        #pragma unroll
        for (int off = 1; off <= 4; off <<= 1) {
            om *= __shfl_xor(om, off, 64);
            sc += __shfl_xor(sc, off, 64);
        }
        if ((lane & 7) == 0) acc_srow += sc;

        if (cb == 0) {                    // row-max > 0.99 counter
            float pm = p;
            #pragma unroll
            for (int off = 32; off >= 1; off >>= 1)
                pm = fmaxf(pm, __shfl_xor(pm, off, 64));
            if (lane == 0 && pm > 0.99f) acc_sel += 1.0f;
        }

        // tile rowsum of D -> nnz contribution with register-resident p
        float ds = d;
        #pragma unroll
        for (int off = 32; off >= 1; off >>= 1)
            ds += __shfl_xor(ds, off, 64);
        nnz_l += ds * p;

        // broadcast the 8 per-channel q values; update column products.
        // (1 - d*(1-q)) == fmaf(d, q-1, 1): exact for d in {0,1}
        float q0 = __shfl(om,  0, 64), q1 = __shfl(om,  8, 64);
        float q2 = __shfl(om, 16, 64), q3 = __shfl(om, 24, 64);
        float q4 = __shfl(om, 32, 64), q5 = __shfl(om, 40, 64);
        float q6 = __shfl(om, 48, 64), q7 = __shfl(om, 56, 64);
        pr[0] *= fmaf(d, q0 - 1.f, 1.f);
        pr[1] *= fmaf(d, q1 - 1.f, 1.f);
        pr[2] *= fmaf(d, q2 - 1.f, 1.f);
        pr[3] *= fmaf(d, q3 - 1.f, 1.f);
        pr[4] *= fmaf(d, q4 - 1.f, 1.f);
        pr[5] *= fmaf(d, q5 - 1.f, 1.f);
        pr[6] *= fmaf(d, q6 - 1.f, 1.f);
        pr[7] *= fmaf(d, q7 - 1.f, 1.f);
    }

    // stage per-wave results, combine across the block's 8 waves
    #pragma unroll
    for (int ch = 0; ch < 8; ++ch) partp[w][ch][lane] = pr[ch];
    rn[w][lane] = nnz_l;
    if ((lane & 7) == 0) rp[w][lane >> 3] = acc_srow;
    if (lane == 0) rsel[w] = acc_sel;
    __syncthreads();

    {   // 512 threads cover 64 cols x 8 ch exactly
        const int cl = tid & 63, ch = tid >> 6;
        float v = partp[0][ch][cl] * partp[1][ch][cl]
                * partp[2][ch][cl] * partp[3][ch][cl]
                * partp[4][ch][cl] * partp[5][ch][cl]
                * partp[6][ch][cl] * partp[7][ch][cl];
        ws[WS_CP + rc * 8192 + ch * 1024 + cb * 64 + cl] = v;  // coalesced
    }
    if (w == 0) {
        float v = rn[0][lane] + rn[1][lane] + rn[2][lane] + rn[3][lane]
                + rn[4][lane] + rn[5][lane] + rn[6][lane] + rn[7][lane];
        ws[WS_NP + blockIdx.x * 64 + lane] = v;
    }
    if (cb == 0 && tid < 8) {
        float v = 0.f;
        #pragma unroll
        for (int ww = 0; ww < 8; ++ww) v += rp[ww][tid];
        ws[WS_NR + rc * 8 + tid] = v;
    }
    if (cb == 0 && tid == 0) {
        float v = 0.f;
        #pragma unroll
        for (int ww = 0; ww < 8; ++ww) v += rsel[ww];
        ws[WS_SEL + rc] = v;
    }
}

// ---------------------------------------------------------------- kernel 2
// Single block, 1024 threads: all final reductions + 97-float tail.
__global__ __launch_bounds__(1024) void k2(const float* __restrict__ ws,
                                           float* __restrict__ out)
{
    const int tid = threadIdx.x;
    __shared__ float red[1024];
    __shared__ float np[8][64];
    __shared__ float nc8[8], nr8[8];

    // --- num_col: product over 16 row-chunks, then 1 - prod, sum over cols.
    // thread -> (ch = tid>>7, 8 cols strided by 128): coalesced reads.
    {
        const int ch = tid >> 7;
        const int c0 = tid & 127;
        float ncl = 0.f;
        #pragma unroll
        for (int j = 0; j < 8; ++j) {
            const float* base = ws + WS_CP + ch * 1024 + j * 128 + c0;
            float prod = base[0];
            #pragma unroll
            for (int rc = 1; rc < 16; ++rc) prod *= base[rc * 8192];
            ncl += 1.0f - prod;
        }
        red[tid] = ncl;
    }

    // --- nnz partials: 512 threads, 8 slices of the 256 blocks
    if (tid < 512) {
        const int l = tid & 63, h = tid >> 6;
        const float* b = ws + WS_NP + h * 32 * 64 + l;
        float v = 0.f;
        #pragma unroll
        for (int bb = 0; bb < 32; ++bb) v += b[bb * 64];
        np[h][l] = v;
    }
    if (tid >= 512 && tid < 520) {       // num_row
        const int ch = tid - 512;
        float v = 0.f;
        #pragma unroll
        for (int rc = 0; rc < 16; ++rc) v += ws[WS_NR + rc * 8 + ch];
        nr8[ch] = v;
    }
    if (tid == 520) {                    // num_row_sel
        float v = 0.f;
        #pragma unroll
        for (int rc = 0; rc < 16; ++rc) v += ws[WS_SEL + rc];
        out[OFF_SEL] = v;
    }
    __syncthreads();

    // reduce num_col within each 128-thread (per-ch) group
    #pragma unroll
    for (int off = 64; off >= 1; off >>= 1) {
        if ((tid & 127) < off) red[tid] += red[tid + off];
        __syncthreads();
    }
    if ((tid & 127) == 0) nc8[tid >> 7] = red[tid];
    __syncthreads();

    // wave 0 finishes: nnz, max/sum over ba, tail outputs
    if (tid < 64) {
        float nnzv = np[0][tid] + np[1][tid] + np[2][tid] + np[3][tid]
                   + np[4][tid] + np[5][tid] + np[6][tid] + np[7][tid];
        out[OFF_NNZ + tid] = nnzv;
        float sum = nnzv, mx = nnzv;
        #pragma unroll
        for (int off = 1; off <= 4; off <<= 1) {
            sum += __shfl_xor(sum, off, 64);
            mx = fmaxf(mx, __shfl_xor(mx, off, 64));
        }
        if ((tid & 7) == 0) {
            const int ch = tid >> 3;
            const float nr = nr8[ch], nc = nc8[ch];
            out[OFF_TOT  + ch] = mx + nc + nr;
            out[OFF_MAX  + ch] = mx;
            out[OFF_NCOL + ch] = nc;
            out[OFF_NROW + ch] = nr;
            out[OFF_DEN  + ch] = sum / nr / nc;
        }
    }
}

extern "C" void kernel_launch(void* const* d_in, const int* in_sizes, int n_in,
                              void* d_out, int out_size, void* d_ws, size_t ws_size,
                              hipStream_t stream) {
    const float* W = (const float*)d_in[0];
    const float* D = (const float*)d_in[1];
    const float* g = (const float*)d_in[2];
    float* out = (float*)d_out;
    float* ws  = (float*)d_ws;

    k1<<<256, 512, 0, stream>>>(W, D, g, out, ws);
    k2<<<1,  1024, 0, stream>>>(ws, out);
}

// Round 5
// 77.127 us; speedup vs baseline: 1.1901x; 1.1901x over previous
//
#include <hip/hip_runtime.h>
#include <math.h>

#define R 2048
#define C 1024
#define CH 8
#define K 64  // CH*BA

// Output layout (floats), reference return order:
#define OFF_P     0
#define OFF_TOT   (R*K)            // 131072
#define OFF_MAX   (OFF_TOT + 8)
#define OFF_NCOL  (OFF_MAX + 8)
#define OFF_NROW  (OFF_NCOL + 8)
#define OFF_NNZ   (OFF_NROW + 8)
#define OFF_DEN   (OFF_NNZ + 64)
#define OFF_SEL   (OFF_DEN + 8)

// ws layout (floats):
#define WS_LQ   0          // lq2[R][8]: clamped log2 of per-(row,ch) prod(1-p)
#define WS_COL  16384      // colacc[8][1024]: zeroed by k1, atomics from k2
#define WS_NP   24576      // nnzpart[256][64]
#define WS_NR   40960      // nrpart[256][8]
#define WS_SEL  43008      // selpart[256]

// ---------------------------------------------------------------- kernel 1
// One row per wave (2048 waves). Softmax -> P, lq2, D rowsum -> nnz partial.
// Also zeroes colacc for k2's atomics (k2 starts only after k1 retires).
__global__ __launch_bounds__(512) void k1(
    const float* __restrict__ W, const float* __restrict__ Dm,
    const float* __restrict__ g, float* __restrict__ P,
    float* __restrict__ ws)
{
    const int tid  = threadIdx.x;
    const int lane = tid & 63;
    const int w    = tid >> 6;              // wave 0..7
    const int row  = blockIdx.x * 8 + w;

    if (tid < 32) ws[WS_COL + blockIdx.x * 32 + tid] = 0.0f;

    // softmax over the row's 64 logits
    float z = W[row * K + lane] + g[row * K + lane];
    float m = z;
    #pragma unroll
    for (int off = 32; off >= 1; off >>= 1)
        m = fmaxf(m, __shfl_xor(m, off, 64));
    float e = __expf(z - m);
    float s = e;
    #pragma unroll
    for (int off = 32; off >= 1; off >>= 1)
        s += __shfl_xor(s, off, 64);
    float p = e * __builtin_amdgcn_rcpf(s);
    P[row * K + lane] = p;

    // D rowsum (coalesced float4, whole wave on one 4KB row)
    const float4* Drow = (const float4*)(Dm + (size_t)row * C);
    float ds = 0.0f;
    #pragma unroll
    for (int j = 0; j < 4; ++j) {
        float4 v = Drow[lane + 64 * j];
        ds += (v.x + v.y) + (v.z + v.w);
    }
    #pragma unroll
    for (int off = 32; off >= 1; off >>= 1)
        ds += __shfl_xor(ds, off, 64);

    // per-channel (8-lane group) product of (1-p), sum of p
    float om = 1.0f - p, sc = p;
    #pragma unroll
    for (int off = 1; off <= 4; off <<= 1) {
        om *= __shfl_xor(om, off, 64);
        sc += __shfl_xor(sc, off, 64);
    }
    if ((lane & 7) == 0)   // clamp: q==0 would give -inf, then 0*-inf = NaN in k2
        ws[WS_LQ + row * CH + (lane >> 3)] =
            fmaxf(__builtin_amdgcn_logf(om), -1.0e30f);

    // row max for num_row_sel
    float pm = p;
    #pragma unroll
    for (int off = 32; off >= 1; off >>= 1)
        pm = fmaxf(pm, __shfl_xor(pm, off, 64));

    // block-level combine (plain stores, no atomics)
    __shared__ float rn[8][64];
    __shared__ float rp[8][8];
    __shared__ float rsel[8];
    rn[w][lane] = p * ds;
    if ((lane & 7) == 0) rp[w][lane >> 3] = sc;
    if (lane == 0) rsel[w] = (pm > 0.99f) ? 1.0f : 0.0f;
    __syncthreads();

    if (tid < 64) {
        float v = rn[0][tid] + rn[1][tid] + rn[2][tid] + rn[3][tid]
                + rn[4][tid] + rn[5][tid] + rn[6][tid] + rn[7][tid];
        ws[WS_NP + blockIdx.x * 64 + tid] = v;
    }
    if (tid < 8) {
        float v = 0.0f;
        #pragma unroll
        for (int ww = 0; ww < 8; ++ww) v += rp[ww][tid];
        ws[WS_NR + blockIdx.x * 8 + tid] = v;
    }
    if (tid == 0) {
        float v = 0.0f;
        #pragma unroll
        for (int ww = 0; ww < 8; ++ww) v += rsel[ww];
        ws[WS_SEL + blockIdx.x] = v;
    }
}

// ---------------------------------------------------------------- kernel 2
// 256 blocks = 4 col-tiles(256) x 64 row-chunks(32). Hot loop: 1 coalesced D
// load + 1 wave-uniform lq2 row (scalarized s_load) + 8 fmac. 8 atomics/thread.
__global__ __launch_bounds__(256) void k2(
    const float* __restrict__ Dm, float* __restrict__ ws)
{
    const int tid = threadIdx.x;
    const int ct  = blockIdx.x & 3;
    const int rc  = blockIdx.x >> 2;
    const int col = ct * 256 + tid;

    float l0=0,l1=0,l2=0,l3=0,l4=0,l5=0,l6=0,l7=0;
    const int r0 = rc * 32;
    #pragma unroll 4
    for (int i = 0; i < 32; ++i) {
        const int r = r0 + i;
        float d = Dm[(size_t)r * C + col];
        const float* lr = ws + WS_LQ + r * CH;   // wave-uniform address
        l0 += d * lr[0]; l1 += d * lr[1]; l2 += d * lr[2]; l3 += d * lr[3];
        l4 += d * lr[4]; l5 += d * lr[5]; l6 += d * lr[6]; l7 += d * lr[7];
    }
    float* ca = ws + WS_COL;
    atomicAdd(&ca[0 * 1024 + col], l0);
    atomicAdd(&ca[1 * 1024 + col], l1);
    atomicAdd(&ca[2 * 1024 + col], l2);
    atomicAdd(&ca[3 * 1024 + col], l3);
    atomicAdd(&ca[4 * 1024 + col], l4);
    atomicAdd(&ca[5 * 1024 + col], l5);
    atomicAdd(&ca[6 * 1024 + col], l6);
    atomicAdd(&ca[7 * 1024 + col], l7);
}

// ---------------------------------------------------------------- kernel 3
// Single block: colacc -> num_col, partial reductions, 97-float tail.
__global__ __launch_bounds__(1024) void k3(const float* __restrict__ ws,
                                           float* __restrict__ out)
{
    const int tid = threadIdx.x;
    __shared__ float red[1024];
    __shared__ float npr[16][64];
    __shared__ float nrr[8][8];
    __shared__ float selr[64];
    __shared__ float nc8[8];

    {   // num_col: 1 - 2^colacc, per-ch partial over 8 cols each
        const int ch = tid >> 7, c0 = tid & 127;
        float ncl = 0.0f;
        #pragma unroll
        for (int j = 0; j < 8; ++j)
            ncl += 1.0f - __builtin_amdgcn_exp2f(
                              ws[WS_COL + ch * 1024 + j * 128 + c0]);
        red[tid] = ncl;
    }
    {   // nnz partials: 16 groups x 16 blocks each
        const int l = tid & 63, grp = tid >> 6;
        float v = 0.0f;
        #pragma unroll
        for (int b = 0; b < 16; ++b)
            v += ws[WS_NP + (grp * 16 + b) * 64 + l];
        npr[grp][l] = v;
    }
    if (tid < 64) {
        const int ch = tid & 7, grp = tid >> 3;
        float v = 0.0f;
        #pragma unroll
        for (int b = 0; b < 32; ++b)
            v += ws[WS_NR + (grp * 32 + b) * CH + ch];
        nrr[grp][ch] = v;
        float sv = 0.0f;
        #pragma unroll
        for (int j = 0; j < 4; ++j)
            sv += ws[WS_SEL + j * 64 + tid];
        selr[tid] = sv;
    }
    __syncthreads();

    // reduce num_col within each per-ch 128-thread group
    #pragma unroll
    for (int off = 64; off >= 1; off >>= 1) {
        if ((tid & 127) < off) red[tid] += red[tid + off];
        __syncthreads();
    }
    if ((tid & 127) == 0) nc8[tid >> 7] = red[tid];
    __syncthreads();

    if (tid < 64) {
        float nnzv = 0.0f;
        #pragma unroll
        for (int g2 = 0; g2 < 16; ++g2) nnzv += npr[g2][tid];
        out[OFF_NNZ + tid] = nnzv;

        float sum = nnzv, mx = nnzv;
        #pragma unroll
        for (int off = 1; off <= 4; off <<= 1) {
            sum += __shfl_xor(sum, off, 64);
            mx = fmaxf(mx, __shfl_xor(mx, off, 64));
        }
        float sv = selr[tid];
        #pragma unroll
        for (int off = 32; off >= 1; off >>= 1)
            sv += __shfl_xor(sv, off, 64);
        if (tid == 0) out[OFF_SEL] = sv;

        if ((tid & 7) == 0) {
            const int ch = tid >> 3;
            float nr = 0.0f;
            #pragma unroll
            for (int g2 = 0; g2 < 8; ++g2) nr += nrr[g2][ch];
            const float nc = nc8[ch];
            out[OFF_TOT  + ch] = mx + nc + nr;
            out[OFF_MAX  + ch] = mx;
            out[OFF_NCOL + ch] = nc;
            out[OFF_NROW + ch] = nr;
            out[OFF_DEN  + ch] = sum / nr / nc;
        }
    }
}

extern "C" void kernel_launch(void* const* d_in, const int* in_sizes, int n_in,
                              void* d_out, int out_size, void* d_ws, size_t ws_size,
                              hipStream_t stream) {
    const float* W = (const float*)d_in[0];
    const float* D = (const float*)d_in[1];
    const float* g = (const float*)d_in[2];
    float* out = (float*)d_out;
    float* ws  = (float*)d_ws;

    k1<<<256, 512, 0, stream>>>(W, D, g, out, ws);
    k2<<<256, 256, 0, stream>>>(D, ws);
    k3<<<1,  1024, 0, stream>>>(ws, out);
}